// Round 1
// baseline (417.053 us; speedup 1.0000x reference)
//
#include <hip/hip_runtime.h>

typedef unsigned short u16;
typedef unsigned int   u32;
typedef short short8 __attribute__((ext_vector_type(8)));
typedef float f32x4 __attribute__((ext_vector_type(4)));
typedef _Float16 f16;
typedef f16 f16x2 __attribute__((ext_vector_type(2)));
typedef f16 f16x8 __attribute__((ext_vector_type(8)));

#define B_ 8
#define T_ 1024
#define E_ 1024
#define H_ 16
#define D_ 64
#define BH_ 128

__device__ __forceinline__ float ftanh(float x){
    x = fminf(8.0f, fmaxf(-8.0f, x));
    float e2 = __expf(2.0f * x);
    return 1.0f - 2.0f * __builtin_amdgcn_rcpf(e2 + 1.0f);
}

__device__ __forceinline__ u16 f2h(float x){
    union { f16 h; u16 u; } v; v.h = (f16)x; return v.u;
}

__device__ __forceinline__ float h2f(u16 u){
    union { u16 u; f16 h; } v; v.u = u; return (float)v.h;
}

// ---------------------------------------------------------------------------
// RNN broadcast network, all in the VALU pipe (no LDS on the critical path).
//
// gather16: from per-lane scalar h (f16 in low half of a u32), build 8 f16x2
// regs holding the 16 h-values of this lane's 16-lane row group. Stages:
// quad_perm ^1, ^2 then row_ror 4/8 (all full-rate DPP). The resulting
// per-lane position->source-lane permutation is NOT hardcoded: it is
// self-calibrated at kernel start by pushing the lane id through the network,
// and the weight loads are gathered with those indices.
// ---------------------------------------------------------------------------
#define DPPC(s, ctrl) ((u32)__builtin_amdgcn_update_dpp(0, (int)(s), (ctrl), 0xF, 0xF, false))

struct G8 { u32 r0, r1, r2, r3, r4, r5, r6, r7; };

__device__ __forceinline__ G8 gather16(u32 a){
    G8 g;
    u32 t = DPPC(a, 0xB1);          // quad_perm [1,0,3,2]  (lane^1)
    g.r0 = a | (t << 16);           // (h[l], h[l^1])
    g.r1 = DPPC(g.r0, 0x4E);        // quad_perm [2,3,0,1]  (lane^2)
    g.r2 = DPPC(g.r0, 0x124);       // row_ror:4
    g.r3 = DPPC(g.r1, 0x124);
    g.r4 = DPPC(g.r0, 0x128);       // row_ror:8
    g.r5 = DPPC(g.r1, 0x128);
    g.r6 = DPPC(g.r2, 0x128);      // ror:12 composite
    g.r7 = DPPC(g.r3, 0x128);
    return g;
}

__device__ __forceinline__ float fd(u32 w, u32 x, float acc){
    return __builtin_amdgcn_fdot2(__builtin_bit_cast(f16x2, w),
                                  __builtin_bit_cast(f16x2, x), acc, false);
}

// permlane swaps: exchange with lane^16 / lane^32. The instruction swaps
// halves between two registers; which output holds the partner value is
// calibrated at runtime (sel), so we don't depend on the exact convention.
__device__ __forceinline__ float perm16x(float v, bool sel){
    u32 a = __builtin_bit_cast(u32, v), b = a;
    asm volatile("v_permlane16_swap_b32 %0, %1" : "+v"(a), "+v"(b));
    return __builtin_bit_cast(float, sel ? a : b);
}
__device__ __forceinline__ float perm32x(float v, bool sel){
    u32 a = __builtin_bit_cast(u32, v), b = a;
    asm volatile("v_permlane32_swap_b32 %0, %1" : "+v"(a), "+v"(b));
    return __builtin_bit_cast(float, sel ? a : b);
}

// One recurrence step. Lane l ends with h_next[l].
// Partial-dot split: lane computes rows {(l&15)+16i} over its 16-col slice,
// then reduce-scatters across lane bits 4 and 5 so it keeps exactly row l.
template<bool USEPERM>
__device__ __forceinline__ u32 rnn_step(u32 hbits, const u32 (&W)[4][8], float cbias,
                                        bool q1f, bool q2f, bool sel16, bool sel32)
{
    G8 g = gather16(hbits);
    float p0 = fd(W[0][0], g.r0, 0.f);
    float p1 = fd(W[1][0], g.r0, 0.f);
    float p2 = fd(W[2][0], g.r0, 0.f);
    float p3 = fd(W[3][0], g.r0, 0.f);
    p0 = fd(W[0][1], g.r1, p0); p1 = fd(W[1][1], g.r1, p1);
    p2 = fd(W[2][1], g.r1, p2); p3 = fd(W[3][1], g.r1, p3);
    p0 = fd(W[0][2], g.r2, p0); p1 = fd(W[1][2], g.r2, p1);
    p2 = fd(W[2][2], g.r2, p2); p3 = fd(W[3][2], g.r2, p3);
    p0 = fd(W[0][3], g.r3, p0); p1 = fd(W[1][3], g.r3, p1);
    p2 = fd(W[2][3], g.r3, p2); p3 = fd(W[3][3], g.r3, p3);
    p0 = fd(W[0][4], g.r4, p0); p1 = fd(W[1][4], g.r4, p1);
    p2 = fd(W[2][4], g.r4, p2); p3 = fd(W[3][4], g.r4, p3);
    p0 = fd(W[0][5], g.r5, p0); p1 = fd(W[1][5], g.r5, p1);
    p2 = fd(W[2][5], g.r5, p2); p3 = fd(W[3][5], g.r5, p3);
    p0 = fd(W[0][6], g.r6, p0); p1 = fd(W[1][6], g.r6, p1);
    p2 = fd(W[2][6], g.r6, p2); p3 = fd(W[3][6], g.r6, p3);
    p0 = fd(W[0][7], g.r7, p0); p1 = fd(W[1][7], g.r7, p1);
    p2 = fd(W[2][7], g.r7, p2); p3 = fd(W[3][7], g.r7, p3);

    // reduce-scatter bit4: keep rows with (i&1)==q1, send the others
    float A0 = q1f ? p1 : p0, S0 = q1f ? p0 : p1;
    float A1 = q1f ? p3 : p2, S1 = q1f ? p2 : p3;
    if (USEPERM) {
        A0 += perm16x(S0, sel16);
        A1 += perm16x(S1, sel16);
    } else {
        A0 += __shfl_xor(S0, 16);
        A1 += __shfl_xor(S1, 16);
    }
    // reduce-scatter bit5: keep row l
    float K  = q2f ? A1 : A0;
    float SS = q2f ? A0 : A1;
    float recv = USEPERM ? perm32x(SS, sel32) : __shfl_xor(SS, 32);
    float yv = K + recv;
    return (u32)f2h(ftanh(yv + cbias));
}

// ---------------------------------------------------------------------------
// Kernel 1: fused RNN (blocks 0..127) + q/v projection (blocks 128..).
// RNN: single wave; the 64-wide state broadcast is done entirely in the VALU
// pipe (DPP all-gather + permlane reduce-scatter) -- no LDS round trip on the
// 1023-step critical path (previously ~200 of ~500 cycles/step).
// Proj: unchanged -- q written [bh][t][d], v written TRANSPOSED [bh][d][t].
// ---------------------------------------------------------------------------
__global__ __launch_bounds__(256, 1) void proj_rnn_kernel(
    const float* __restrict__ src, const float* __restrict__ tgt,
    const float* __restrict__ Wq,  const float* __restrict__ Wv,
    const float* __restrict__ Wih, const float* __restrict__ Whh,
    const float* __restrict__ bih, const float* __restrict__ bhh,
    u16* __restrict__ qh, u16* __restrict__ vh, u16* __restrict__ nwh)
{
    int bid = blockIdx.x;
    if (bid < BH_) {
        // ---- RNN role: single wave, no barriers, no LDS ----
        if (threadIdx.x >= 64) return;
        const int b = bid >> 4, h = bid & 15;
        const int l = threadIdx.x;
        const bool q1f = (l & 16) != 0;
        const bool q2f = (l & 32) != 0;

        // gather-network calibration: payload = lane id (exact in f16).
        // After the network, position p holds the f16 of its SOURCE lane id,
        // which is also the k-index of the h-value that will sit there.
        G8 cg = gather16((u32)f2h((float)l));
        int kidx[16];
        kidx[0]  = (int)h2f((u16)(cg.r0 & 0xFFFF)); kidx[1]  = (int)h2f((u16)(cg.r0 >> 16));
        kidx[2]  = (int)h2f((u16)(cg.r1 & 0xFFFF)); kidx[3]  = (int)h2f((u16)(cg.r1 >> 16));
        kidx[4]  = (int)h2f((u16)(cg.r2 & 0xFFFF)); kidx[5]  = (int)h2f((u16)(cg.r2 >> 16));
        kidx[6]  = (int)h2f((u16)(cg.r3 & 0xFFFF)); kidx[7]  = (int)h2f((u16)(cg.r3 >> 16));
        kidx[8]  = (int)h2f((u16)(cg.r4 & 0xFFFF)); kidx[9]  = (int)h2f((u16)(cg.r4 >> 16));
        kidx[10] = (int)h2f((u16)(cg.r5 & 0xFFFF)); kidx[11] = (int)h2f((u16)(cg.r5 >> 16));
        kidx[12] = (int)h2f((u16)(cg.r6 & 0xFFFF)); kidx[13] = (int)h2f((u16)(cg.r6 >> 16));
        kidx[14] = (int)h2f((u16)(cg.r7 & 0xFFFF)); kidx[15] = (int)h2f((u16)(cg.r7 >> 16));

        // permlane swap calibration (which output holds lane^16 / lane^32)
        u32 sx = (u32)l, sy = (u32)l;
        asm volatile("v_permlane16_swap_b32 %0, %1" : "+v"(sx), "+v"(sy));
        const bool sel16 = (sx == (u32)(l ^ 16));
        const bool ok16  = sel16 || (sy == (u32)(l ^ 16));
        u32 tx = (u32)l, ty = (u32)l;
        asm volatile("v_permlane32_swap_b32 %0, %1" : "+v"(tx), "+v"(ty));
        const bool sel32 = (tx == (u32)(l ^ 32));
        const bool ok32  = sel32 || (ty == (u32)(l ^ 32));

        // weights: rows (l&15)+16i, columns gathered by kidx, packed f16x2
        const float* WI = Wih + (size_t)h * D_ * D_;
        const float* WH = Whh + (size_t)h * D_ * D_;
        float cbias = bih[h * D_ + l] + bhh[h * D_ + l];
        u32 wm[4][8], wn[4][8];
        #pragma unroll
        for (int i = 0; i < 4; ++i) {
            const float* wiR = WI + (size_t)((l & 15) + 16 * i) * D_;
            const float* whR = WH + (size_t)((l & 15) + 16 * i) * D_;
            #pragma unroll
            for (int j = 0; j < 8; ++j) {
                int k0 = kidx[2 * j], k1 = kidx[2 * j + 1];
                float wI0 = wiR[k0], wI1 = wiR[k1];
                float wH0 = whR[k0], wH1 = whR[k1];
                wn[i][j] = (u32)f2h(wI0)       | ((u32)f2h(wI1)       << 16);
                wm[i][j] = (u32)f2h(wI0 + wH0) | ((u32)f2h(wI1 + wH1) << 16);
            }
        }
        // pin the recurrent weights VGPR-resident across the 1023-step loop
        #pragma unroll
        for (int i = 0; i < 4; ++i)
            #pragma unroll
            for (int j = 0; j < 8; ++j)
                asm volatile("" : "+v"(wm[i][j]));
        asm volatile("" : "+v"(cbias));

        u16* nwp = nwh + (size_t)bid * T_ * D_;
        u32 hb = (u32)f2h(tgt[(size_t)b * T_ * E_ + h * D_ + l]);  // k0

        if (__all(ok16 && ok32)) {
            hb = rnn_step<true>(hb, wn, cbias, q1f, q2f, sel16, sel32);   // h1
            nwp[l] = (u16)hb;
            #pragma unroll 1
            for (int t = 1; t < T_; ++t) {
                hb = rnn_step<true>(hb, wm, cbias, q1f, q2f, sel16, sel32);
                nwp[(size_t)t * D_ + l] = (u16)hb;
            }
        } else {
            // semantics fallback: ds_bpermute-based shuffles (slower, correct)
            hb = rnn_step<false>(hb, wn, cbias, q1f, q2f, sel16, sel32);
            nwp[l] = (u16)hb;
            #pragma unroll 1
            for (int t = 1; t < T_; ++t) {
                hb = rnn_step<false>(hb, wm, cbias, q1f, q2f, sel16, sel32);
                nwp[(size_t)t * D_ + l] = (u16)hb;
            }
        }
    } else {
        // ---- projection role (unchanged) ----
        int pb   = bid - BH_;          // 0 .. 4095
        int bh   = pb >> 5;            // (b*16+h)
        int tile = pb & 31;            // 32 t-rows per block
        int b = bh >> 4, h = bh & 15;
        int e  = threadIdx.x & 63;
        int tg = threadIdx.x >> 6;
        int t0 = tile * 32 + tg * 8;

        const float* wq = Wq + (size_t)h * D_ * D_ + e;  // column e, stride 64
        const float* wv = Wv + (size_t)h * D_ * D_ + e;
        const float* s0 = src + ((size_t)b * T_ + t0) * E_ + h * D_;
        const float* g0 = tgt + ((size_t)b * T_ + t0) * E_ + h * D_;

        float aq[8] = {0,0,0,0,0,0,0,0};
        float av[8] = {0,0,0,0,0,0,0,0};
        #pragma unroll 4
        for (int d4 = 0; d4 < 16; ++d4) {
            float q0 = wq[(4*d4+0)*64], q1 = wq[(4*d4+1)*64],
                  q2 = wq[(4*d4+2)*64], q3 = wq[(4*d4+3)*64];
            float v0 = wv[(4*d4+0)*64], v1 = wv[(4*d4+1)*64],
                  v2 = wv[(4*d4+2)*64], v3 = wv[(4*d4+3)*64];
            #pragma unroll
            for (int j = 0; j < 8; ++j) {
                float4 x = *(const float4*)(s0 + (size_t)j * E_ + 4*d4);
                float4 y = *(const float4*)(g0 + (size_t)j * E_ + 4*d4);
                aq[j] += x.x*q0 + x.y*q1 + x.z*q2 + x.w*q3;
                av[j] += y.x*v0 + y.y*v1 + y.z*v2 + y.w*v3;
            }
        }
        // q: [bh][t][e], coalesced u16 rows; fold 1/256 score scale into q
        u16* qp = qh + ((size_t)bh * T_ + t0) * D_ + e;
        #pragma unroll
        for (int j = 0; j < 8; ++j) qp[(size_t)j * D_] = f2h(aq[j] * (1.0f/256.0f));
        // v: TRANSPOSED [bh][d=e][t], one b128 per thread
        f16x8 vv;
        #pragma unroll
        for (int j = 0; j < 8; ++j) vv[j] = (f16)av[j];
        *(f16x8*)(vh + ((size_t)bh * D_ + e) * T_ + t0) = vv;
    }
}

// ---------------------------------------------------------------------------
// Kernel 2: flash attention, f16 MFMA 16x16x32, fused output projection.
// (unchanged this round)
// ---------------------------------------------------------------------------
#define MFMA16(a, b, c) __builtin_amdgcn_mfma_f32_16x16x32_f16(a, b, c, 0, 0, 0)

__global__ __launch_bounds__(256) void attn_kernel(
    const u16* __restrict__ qh,   // [bh][t][64] f16, pre-scaled 1/256
    const u16* __restrict__ kh,   // nw states [bh][t][64] f16
    const u16* __restrict__ vh,   // V^T [bh][d][t] f16
    const float* __restrict__ Wo, // [H][64][64] fp32
    float* __restrict__ out)      // [B][T][E] fp32
{
    __shared__ __align__(16) u16 Klds[64 * 64];     // keys; later Wo^T
    __shared__ __align__(16) u16 Vlds[64 * 64];     // V^T: row=d, col=key
    __shared__ __align__(16) u16 Plds[4][16 * 64];  // per-wave P / O relayout

    const int tid  = threadIdx.x;
    const int lane = tid & 63;
    const int w    = tid >> 6;
    const int l15  = lane & 15;
    const int quad = lane >> 4;
    const int sw   = lane & 7;
    const int bh   = blockIdx.y;
    const int qt   = blockIdx.x;

    const size_t base  = (size_t)bh * T_ * D_;
    const size_t vbase = (size_t)bh * D_ * T_;

    f16x8 aq0, aq1;
    {
        int qrow = qt * 64 + w * 16 + l15;
        const f16x8* qp = (const f16x8*)(qh + base + (size_t)qrow * 64 + quad * 8);
        aq0 = qp[0];
        aq1 = qp[4];
    }

    f32x4 oacc[4];
    #pragma unroll
    for (int i = 0; i < 4; ++i) oacc[i] = (f32x4){0.f, 0.f, 0.f, 0.f};
    float lrun[4] = {0.f, 0.f, 0.f, 0.f};

    u16* Pw = Plds[w];

    #pragma unroll 1
    for (int kt = 0; kt < 16; ++kt) {
        // ---- stage K rows + V^T rows, both vectorized b128, swizzled ----
        #pragma unroll
        for (int i = 0; i < 2; ++i) {
            int ch = tid + 256 * i;          // 512 chunks of 8 u16
            int r = ch >> 3, cc = ch & 7;
            short8 kval = *(const short8*)(kh + base + (size_t)(kt * 64 + r) * 64 + cc * 8);
            *(short8*)&Klds[r * 64 + ((cc ^ (r & 7)) * 8)] = kval;
            short8 vval = *(const short8*)(vh + vbase + (size_t)r * T_ + kt * 64 + cc * 8);
            *(short8*)&Vlds[r * 64 + ((cc ^ (r & 7)) * 8)] = vval;
        }
        __syncthreads();

        // ---- S = Q K^T ----
        f32x4 sacc[4];
        #pragma unroll
        for (int u = 0; u < 4; ++u) {
            sacc[u] = (f32x4){0.f, 0.f, 0.f, 0.f};
            int row = 16 * u + l15;
            f16x8 bk0 = *(const f16x8*)&Klds[row * 64 + (((quad + 0) ^ sw) * 8)];
            f16x8 bk1 = *(const f16x8*)&Klds[row * 64 + (((quad + 4) ^ sw) * 8)];
            sacc[u] = MFMA16(aq0, bk0, sacc[u]);
            sacc[u] = MFMA16(aq1, bk1, sacc[u]);
        }

        // ---- softmax accumulation (no max: shift-invariant, |s| tiny) ----
        float pr[4][4];
        #pragma unroll
        for (int r = 0; r < 4; ++r) {
            float rs = 0.f;
            #pragma unroll
            for (int u = 0; u < 4; ++u) {
                float pv = __expf(sacc[u][r]);
                pr[u][r] = pv;
                rs += pv;
            }
            #pragma unroll
            for (int off = 1; off < 16; off <<= 1)
                rs += __shfl_xor(rs, off, 16);
            lrun[r] += rs;
        }

        // ---- P -> per-wave LDS (C-layout -> A-fragment layout) ----
        #pragma unroll
        for (int u = 0; u < 4; ++u) {
            int col = 16 * u + l15;
            #pragma unroll
            for (int r = 0; r < 4; ++r) {
                int row = quad * 4 + r;
                Pw[row * 64 + (((col >> 3) ^ (row & 7)) * 8) + (col & 7)] = f2h(pr[u][r]);
            }
        }

        // ---- O += P V ----
        #pragma unroll
        for (int kc = 0; kc < 2; ++kc) {
            f16x8 ap = *(const f16x8*)&Pw[l15 * 64 + (((quad + 4 * kc) ^ sw) * 8)];
            #pragma unroll
            for (int nt = 0; nt < 4; ++nt) {
                int drow = 16 * nt + l15;
                f16x8 bv = *(const f16x8*)&Vlds[drow * 64 + (((quad + 4 * kc) ^ sw) * 8)];
                oacc[nt] = MFMA16(ap, bv, oacc[nt]);
            }
        }
        __syncthreads();
    }

    // ---- fused output projection: out_tile = (O/l) * Wo[h] ----
    const int b  = bh >> 4, hh = bh & 15;
    {
        const float* wo = Wo + (size_t)hh * D_ * D_;
        #pragma unroll
        for (int i = 0; i < 2; ++i) {
            int ch = tid + 256 * i;          // e = ch>>3, dc = ch&7
            int e = ch >> 3, dc = ch & 7;
            short8 vch;
            #pragma unroll
            for (int j = 0; j < 8; ++j)
                vch[j] = (short)f2h(wo[(size_t)(dc * 8 + j) * D_ + e]);
            *(short8*)&Klds[e * 64 + ((dc ^ (e & 7)) * 8)] = vch;
        }
    }
    #pragma unroll
    for (int nt = 0; nt < 4; ++nt) {
        int col = 16 * nt + l15;             // d
        #pragma unroll
        for (int r = 0; r < 4; ++r) {
            int row = quad * 4 + r;          // q
            Pw[row * 64 + (((col >> 3) ^ (row & 7)) * 8) + (col & 7)] =
                f2h(oacc[nt][r] / lrun[r]);
        }
    }
    __syncthreads();    // Wo^T staging visible to all waves

    f16x8 ao0 = *(const f16x8*)&Pw[l15 * 64 + (((quad + 0) ^ sw) * 8)];
    f16x8 ao1 = *(const f16x8*)&Pw[l15 * 64 + (((quad + 4) ^ sw) * 8)];
    f32x4 oo[4];
    #pragma unroll
    for (int nt = 0; nt < 4; ++nt) {
        oo[nt] = (f32x4){0.f, 0.f, 0.f, 0.f};
        int erow = 16 * nt + l15;
        f16x8 b0 = *(const f16x8*)&Klds[erow * 64 + (((quad + 0) ^ (erow & 7)) * 8)];
        f16x8 b1 = *(const f16x8*)&Klds[erow * 64 + (((quad + 4) ^ (erow & 7)) * 8)];
        oo[nt] = MFMA16(ao0, b0, oo[nt]);
        oo[nt] = MFMA16(ao1, b1, oo[nt]);
    }
    #pragma unroll
    for (int nt = 0; nt < 4; ++nt) {
        #pragma unroll
        for (int r = 0; r < 4; ++r) {
            int qg = qt * 64 + w * 16 + quad * 4 + r;
            int e  = 16 * nt + l15;
            out[((size_t)b * T_ + qg) * E_ + hh * D_ + e] = oo[nt][r];
        }
    }
}

// ---------------------------------------------------------------------------
extern "C" void kernel_launch(void* const* d_in, const int* in_sizes, int n_in,
                              void* d_out, int out_size, void* d_ws, size_t ws_size,
                              hipStream_t stream)
{
    const float* src = (const float*)d_in[0];
    const float* tgt = (const float*)d_in[1];
    const float* Wq  = (const float*)d_in[2];
    const float* Wv  = (const float*)d_in[3];
    const float* Wo  = (const float*)d_in[4];
    const float* Wih = (const float*)d_in[5];
    const float* Whh = (const float*)d_in[6];
    const float* bih = (const float*)d_in[7];
    const float* bhh = (const float*)d_in[8];
    float* out = (float*)d_out;

    char* ws = (char*)d_ws;
    u16* qh  = (u16*)(ws);                             // [bh][t][d] 16 MB
    u16* vh  = (u16*)(ws + (size_t)16 * 1024 * 1024);  // V^T [bh][d][t] 16 MB
    u16* nwh = (u16*)(ws + (size_t)32 * 1024 * 1024);  // [bh][t][d] 16 MB

    (void)in_sizes; (void)n_in; (void)out_size; (void)ws_size;

    // blocks [0,128) = RNN chains; [128, 128+4096) = q/v projection
    proj_rnn_kernel<<<dim3(BH_ + 4096), 256, 0, stream>>>(
        src, tgt, Wq, Wv, Wih, Whh, bih, bhh, qh, vh, nwh);
    attn_kernel<<<dim3(16, BH_), 256, 0, stream>>>(qh, nwh, vh, Wo, out);
}

// Round 2
// 413.304 us; speedup vs baseline: 1.0091x; 1.0091x over previous
//
#include <hip/hip_runtime.h>

typedef unsigned short u16;
typedef unsigned int   u32;
typedef short short8 __attribute__((ext_vector_type(8)));
typedef float f32x4 __attribute__((ext_vector_type(4)));
typedef _Float16 f16;
typedef f16 f16x2 __attribute__((ext_vector_type(2)));
typedef f16 f16x8 __attribute__((ext_vector_type(8)));

#define B_ 8
#define T_ 1024
#define E_ 1024
#define H_ 16
#define D_ 64
#define BH_ 128

__device__ __forceinline__ float fexp2(float x){
#if __has_builtin(__builtin_amdgcn_exp2f)
    return __builtin_amdgcn_exp2f(x);
#else
    return exp2f(x);
#endif
}

// tanh via exp2: tanh(x) = 1 - 2/(exp(2x)+1); clamp in log2 domain.
__device__ __forceinline__ float ftanh(float x){
    float xl = fminf(23.0f, fmaxf(-23.0f, x * 2.885390081777927f)); // 2*log2(e)*x
    float e2 = fexp2(xl);
    return 1.0f - 2.0f * __builtin_amdgcn_rcpf(e2 + 1.0f);
}

__device__ __forceinline__ u16 f2h(float x){
    union { f16 h; u16 u; } v; v.h = (f16)x; return v.u;
}

__device__ __forceinline__ float h2f(u16 u){
    union { u16 u; f16 h; } v; v.u = u; return (float)v.h;
}

// ---------------------------------------------------------------------------
// RNN broadcast network, all in the VALU pipe (no LDS on the critical path).
// gather16 permutation is self-calibrated (lane-id payload); permlane swap
// output convention likewise. See round-1 notes.
// ---------------------------------------------------------------------------
#define DPPC(s, ctrl) ((u32)__builtin_amdgcn_update_dpp(0, (int)(s), (ctrl), 0xF, 0xF, false))

struct G8 { u32 r0, r1, r2, r3, r4, r5, r6, r7; };

__device__ __forceinline__ G8 gather16(u32 a){
    G8 g;
    u32 t = DPPC(a, 0xB1);          // quad_perm [1,0,3,2]  (lane^1)
    g.r0 = a | (t << 16);           // (h[l], h[l^1])
    g.r1 = DPPC(g.r0, 0x4E);        // quad_perm [2,3,0,1]  (lane^2)
    g.r2 = DPPC(g.r0, 0x124);       // row_ror:4
    g.r3 = DPPC(g.r1, 0x124);
    g.r4 = DPPC(g.r0, 0x128);       // row_ror:8
    g.r5 = DPPC(g.r1, 0x128);
    g.r6 = DPPC(g.r2, 0x128);       // ror:12 composite
    g.r7 = DPPC(g.r3, 0x128);
    return g;
}

__device__ __forceinline__ float fd(u32 w, u32 x, float acc){
    return __builtin_amdgcn_fdot2(__builtin_bit_cast(f16x2, w),
                                  __builtin_bit_cast(f16x2, x), acc, false);
}

__device__ __forceinline__ float perm16x(float v, bool sel){
    u32 a = __builtin_bit_cast(u32, v), b = a;
    asm volatile("v_permlane16_swap_b32 %0, %1" : "+v"(a), "+v"(b));
    return __builtin_bit_cast(float, sel ? a : b);
}
__device__ __forceinline__ float perm32x(float v, bool sel){
    u32 a = __builtin_bit_cast(u32, v), b = a;
    asm volatile("v_permlane32_swap_b32 %0, %1" : "+v"(a), "+v"(b));
    return __builtin_bit_cast(float, sel ? a : b);
}

// One recurrence step. Lane l ends with h_next[l].
template<bool USEPERM>
__device__ __forceinline__ u32 rnn_step(u32 hbits, const u32 (&W)[4][8], float cbias,
                                        bool q1f, bool q2f, bool sel16, bool sel32)
{
    G8 g = gather16(hbits);
    float p0 = fd(W[0][0], g.r0, 0.f);
    float p1 = fd(W[1][0], g.r0, 0.f);
    float p2 = fd(W[2][0], g.r0, 0.f);
    float p3 = fd(W[3][0], g.r0, 0.f);
    p0 = fd(W[0][1], g.r1, p0); p1 = fd(W[1][1], g.r1, p1);
    p2 = fd(W[2][1], g.r1, p2); p3 = fd(W[3][1], g.r1, p3);
    p0 = fd(W[0][2], g.r2, p0); p1 = fd(W[1][2], g.r2, p1);
    p2 = fd(W[2][2], g.r2, p2); p3 = fd(W[3][2], g.r2, p3);
    p0 = fd(W[0][3], g.r3, p0); p1 = fd(W[1][3], g.r3, p1);
    p2 = fd(W[2][3], g.r3, p2); p3 = fd(W[3][3], g.r3, p3);
    p0 = fd(W[0][4], g.r4, p0); p1 = fd(W[1][4], g.r4, p1);
    p2 = fd(W[2][4], g.r4, p2); p3 = fd(W[3][4], g.r4, p3);
    p0 = fd(W[0][5], g.r5, p0); p1 = fd(W[1][5], g.r5, p1);
    p2 = fd(W[2][5], g.r5, p2); p3 = fd(W[3][5], g.r5, p3);
    p0 = fd(W[0][6], g.r6, p0); p1 = fd(W[1][6], g.r6, p1);
    p2 = fd(W[2][6], g.r6, p2); p3 = fd(W[3][6], g.r6, p3);
    p0 = fd(W[0][7], g.r7, p0); p1 = fd(W[1][7], g.r7, p1);
    p2 = fd(W[2][7], g.r7, p2); p3 = fd(W[3][7], g.r7, p3);

    // reduce-scatter bit4: keep rows with (i&1)==q1, send the others
    float A0 = q1f ? p1 : p0, S0 = q1f ? p0 : p1;
    float A1 = q1f ? p3 : p2, S1 = q1f ? p2 : p3;
    if (USEPERM) {
        A0 += perm16x(S0, sel16);
        A1 += perm16x(S1, sel16);
    } else {
        A0 += __shfl_xor(S0, 16);
        A1 += __shfl_xor(S1, 16);
    }
    // reduce-scatter bit5: keep row l
    float K  = q2f ? A1 : A0;
    float SS = q2f ? A0 : A1;
    float recv = USEPERM ? perm32x(SS, sel32) : __shfl_xor(SS, 32);
    float yv = K + recv;
    return (u32)f2h(ftanh(yv + cbias));
}

// ---------------------------------------------------------------------------
// Kernel 1: fused RNN (blocks 0..127) + q/v projection (blocks 128..).
// RNN wave runs at s_setprio(3): it is the serial critical path of the whole
// problem and shares its CU with 3-4 throughput-bound proj blocks; round-1
// showed the step cost (~550cy) is ~3x the intrinsic dependent chain, i.e.
// issue-slot contention, which priority arbitration addresses directly.
// ---------------------------------------------------------------------------
__global__ __launch_bounds__(256, 1) void proj_rnn_kernel(
    const float* __restrict__ src, const float* __restrict__ tgt,
    const float* __restrict__ Wq,  const float* __restrict__ Wv,
    const float* __restrict__ Wih, const float* __restrict__ Whh,
    const float* __restrict__ bih, const float* __restrict__ bhh,
    u16* __restrict__ qh, u16* __restrict__ vh, u16* __restrict__ nwh)
{
    int bid = blockIdx.x;
    if (bid < BH_) {
        // ---- RNN role: single wave, no barriers, no LDS ----
        if (threadIdx.x >= 64) return;
        __builtin_amdgcn_s_setprio(3);   // critical-path wave wins issue arbitration
        const int b = bid >> 4, h = bid & 15;
        const int l = threadIdx.x;
        const bool q1f = (l & 16) != 0;
        const bool q2f = (l & 32) != 0;

        // gather-network calibration (lane-id payload, exact in f16)
        G8 cg = gather16((u32)f2h((float)l));
        int kidx[16];
        kidx[0]  = (int)h2f((u16)(cg.r0 & 0xFFFF)); kidx[1]  = (int)h2f((u16)(cg.r0 >> 16));
        kidx[2]  = (int)h2f((u16)(cg.r1 & 0xFFFF)); kidx[3]  = (int)h2f((u16)(cg.r1 >> 16));
        kidx[4]  = (int)h2f((u16)(cg.r2 & 0xFFFF)); kidx[5]  = (int)h2f((u16)(cg.r2 >> 16));
        kidx[6]  = (int)h2f((u16)(cg.r3 & 0xFFFF)); kidx[7]  = (int)h2f((u16)(cg.r3 >> 16));
        kidx[8]  = (int)h2f((u16)(cg.r4 & 0xFFFF)); kidx[9]  = (int)h2f((u16)(cg.r4 >> 16));
        kidx[10] = (int)h2f((u16)(cg.r5 & 0xFFFF)); kidx[11] = (int)h2f((u16)(cg.r5 >> 16));
        kidx[12] = (int)h2f((u16)(cg.r6 & 0xFFFF)); kidx[13] = (int)h2f((u16)(cg.r6 >> 16));
        kidx[14] = (int)h2f((u16)(cg.r7 & 0xFFFF)); kidx[15] = (int)h2f((u16)(cg.r7 >> 16));

        // permlane swap calibration (which output holds lane^16 / lane^32)
        u32 sx = (u32)l, sy = (u32)l;
        asm volatile("v_permlane16_swap_b32 %0, %1" : "+v"(sx), "+v"(sy));
        const bool sel16 = (sx == (u32)(l ^ 16));
        const bool ok16  = sel16 || (sy == (u32)(l ^ 16));
        u32 tx = (u32)l, ty = (u32)l;
        asm volatile("v_permlane32_swap_b32 %0, %1" : "+v"(tx), "+v"(ty));
        const bool sel32 = (tx == (u32)(l ^ 32));
        const bool ok32  = sel32 || (ty == (u32)(l ^ 32));

        // weights: rows (l&15)+16i, columns gathered by kidx, packed f16x2
        const float* WI = Wih + (size_t)h * D_ * D_;
        const float* WH = Whh + (size_t)h * D_ * D_;
        float cbias = bih[h * D_ + l] + bhh[h * D_ + l];
        u32 wm[4][8], wn[4][8];
        #pragma unroll
        for (int i = 0; i < 4; ++i) {
            const float* wiR = WI + (size_t)((l & 15) + 16 * i) * D_;
            const float* whR = WH + (size_t)((l & 15) + 16 * i) * D_;
            #pragma unroll
            for (int j = 0; j < 8; ++j) {
                int k0 = kidx[2 * j], k1 = kidx[2 * j + 1];
                float wI0 = wiR[k0], wI1 = wiR[k1];
                float wH0 = whR[k0], wH1 = whR[k1];
                wn[i][j] = (u32)f2h(wI0)       | ((u32)f2h(wI1)       << 16);
                wm[i][j] = (u32)f2h(wI0 + wH0) | ((u32)f2h(wI1 + wH1) << 16);
            }
        }
        // pin the recurrent weights VGPR-resident across the 1023-step loop
        #pragma unroll
        for (int i = 0; i < 4; ++i)
            #pragma unroll
            for (int j = 0; j < 8; ++j)
                asm volatile("" : "+v"(wm[i][j]));
        asm volatile("" : "+v"(cbias));

        u16* nwp = nwh + (size_t)bid * T_ * D_;
        u32 hb = (u32)f2h(tgt[(size_t)b * T_ * E_ + h * D_ + l]);  // k0

        if (__all(ok16 && ok32)) {
            hb = rnn_step<true>(hb, wn, cbias, q1f, q2f, sel16, sel32);   // h1
            nwp[l] = (u16)hb;
            #pragma unroll 1
            for (int t = 1; t < T_; ++t) {
                hb = rnn_step<true>(hb, wm, cbias, q1f, q2f, sel16, sel32);
                nwp[(size_t)t * D_ + l] = (u16)hb;
            }
        } else {
            // semantics fallback: shuffle-based exchange (slower, correct)
            hb = rnn_step<false>(hb, wn, cbias, q1f, q2f, sel16, sel32);
            nwp[l] = (u16)hb;
            #pragma unroll 1
            for (int t = 1; t < T_; ++t) {
                hb = rnn_step<false>(hb, wm, cbias, q1f, q2f, sel16, sel32);
                nwp[(size_t)t * D_ + l] = (u16)hb;
            }
        }
    } else {
        // ---- projection role (unchanged) ----
        int pb   = bid - BH_;          // 0 .. 4095
        int bh   = pb >> 5;            // (b*16+h)
        int tile = pb & 31;            // 32 t-rows per block
        int b = bh >> 4, h = bh & 15;
        int e  = threadIdx.x & 63;
        int tg = threadIdx.x >> 6;
        int t0 = tile * 32 + tg * 8;

        const float* wq = Wq + (size_t)h * D_ * D_ + e;  // column e, stride 64
        const float* wv = Wv + (size_t)h * D_ * D_ + e;
        const float* s0 = src + ((size_t)b * T_ + t0) * E_ + h * D_;
        const float* g0 = tgt + ((size_t)b * T_ + t0) * E_ + h * D_;

        float aq[8] = {0,0,0,0,0,0,0,0};
        float av[8] = {0,0,0,0,0,0,0,0};
        #pragma unroll 4
        for (int d4 = 0; d4 < 16; ++d4) {
            float q0 = wq[(4*d4+0)*64], q1 = wq[(4*d4+1)*64],
                  q2 = wq[(4*d4+2)*64], q3 = wq[(4*d4+3)*64];
            float v0 = wv[(4*d4+0)*64], v1 = wv[(4*d4+1)*64],
                  v2 = wv[(4*d4+2)*64], v3 = wv[(4*d4+3)*64];
            #pragma unroll
            for (int j = 0; j < 8; ++j) {
                float4 x = *(const float4*)(s0 + (size_t)j * E_ + 4*d4);
                float4 y = *(const float4*)(g0 + (size_t)j * E_ + 4*d4);
                aq[j] += x.x*q0 + x.y*q1 + x.z*q2 + x.w*q3;
                av[j] += y.x*v0 + y.y*v1 + y.z*v2 + y.w*v3;
            }
        }
        // q: [bh][t][e], coalesced u16 rows; fold 1/256 score scale into q
        u16* qp = qh + ((size_t)bh * T_ + t0) * D_ + e;
        #pragma unroll
        for (int j = 0; j < 8; ++j) qp[(size_t)j * D_] = f2h(aq[j] * (1.0f/256.0f));
        // v: TRANSPOSED [bh][d=e][t], one b128 per thread
        f16x8 vv;
        #pragma unroll
        for (int j = 0; j < 8; ++j) vv[j] = (f16)av[j];
        *(f16x8*)(vh + ((size_t)bh * D_ + e) * T_ + t0) = vv;
    }
}

// ---------------------------------------------------------------------------
// Kernel 2: flash attention, f16 MFMA 16x16x32, fused output projection.
// (unchanged this round -- keep attribution clean)
// ---------------------------------------------------------------------------
#define MFMA16(a, b, c) __builtin_amdgcn_mfma_f32_16x16x32_f16(a, b, c, 0, 0, 0)

__global__ __launch_bounds__(256) void attn_kernel(
    const u16* __restrict__ qh,   // [bh][t][64] f16, pre-scaled 1/256
    const u16* __restrict__ kh,   // nw states [bh][t][64] f16
    const u16* __restrict__ vh,   // V^T [bh][d][t] f16
    const float* __restrict__ Wo, // [H][64][64] fp32
    float* __restrict__ out)      // [B][T][E] fp32
{
    __shared__ __align__(16) u16 Klds[64 * 64];     // keys; later Wo^T
    __shared__ __align__(16) u16 Vlds[64 * 64];     // V^T: row=d, col=key
    __shared__ __align__(16) u16 Plds[4][16 * 64];  // per-wave P / O relayout

    const int tid  = threadIdx.x;
    const int lane = tid & 63;
    const int w    = tid >> 6;
    const int l15  = lane & 15;
    const int quad = lane >> 4;
    const int sw   = lane & 7;
    const int bh   = blockIdx.y;
    const int qt   = blockIdx.x;

    const size_t base  = (size_t)bh * T_ * D_;
    const size_t vbase = (size_t)bh * D_ * T_;

    f16x8 aq0, aq1;
    {
        int qrow = qt * 64 + w * 16 + l15;
        const f16x8* qp = (const f16x8*)(qh + base + (size_t)qrow * 64 + quad * 8);
        aq0 = qp[0];
        aq1 = qp[4];
    }

    f32x4 oacc[4];
    #pragma unroll
    for (int i = 0; i < 4; ++i) oacc[i] = (f32x4){0.f, 0.f, 0.f, 0.f};
    float lrun[4] = {0.f, 0.f, 0.f, 0.f};

    u16* Pw = Plds[w];

    #pragma unroll 1
    for (int kt = 0; kt < 16; ++kt) {
        // ---- stage K rows + V^T rows, both vectorized b128, swizzled ----
        #pragma unroll
        for (int i = 0; i < 2; ++i) {
            int ch = tid + 256 * i;          // 512 chunks of 8 u16
            int r = ch >> 3, cc = ch & 7;
            short8 kval = *(const short8*)(kh + base + (size_t)(kt * 64 + r) * 64 + cc * 8);
            *(short8*)&Klds[r * 64 + ((cc ^ (r & 7)) * 8)] = kval;
            short8 vval = *(const short8*)(vh + vbase + (size_t)r * T_ + kt * 64 + cc * 8);
            *(short8*)&Vlds[r * 64 + ((cc ^ (r & 7)) * 8)] = vval;
        }
        __syncthreads();

        // ---- S = Q K^T ----
        f32x4 sacc[4];
        #pragma unroll
        for (int u = 0; u < 4; ++u) {
            sacc[u] = (f32x4){0.f, 0.f, 0.f, 0.f};
            int row = 16 * u + l15;
            f16x8 bk0 = *(const f16x8*)&Klds[row * 64 + (((quad + 0) ^ sw) * 8)];
            f16x8 bk1 = *(const f16x8*)&Klds[row * 64 + (((quad + 4) ^ sw) * 8)];
            sacc[u] = MFMA16(aq0, bk0, sacc[u]);
            sacc[u] = MFMA16(aq1, bk1, sacc[u]);
        }

        // ---- softmax accumulation (no max: shift-invariant, |s| tiny) ----
        float pr[4][4];
        #pragma unroll
        for (int r = 0; r < 4; ++r) {
            float rs = 0.f;
            #pragma unroll
            for (int u = 0; u < 4; ++u) {
                float pv = __expf(sacc[u][r]);
                pr[u][r] = pv;
                rs += pv;
            }
            #pragma unroll
            for (int off = 1; off < 16; off <<= 1)
                rs += __shfl_xor(rs, off, 16);
            lrun[r] += rs;
        }

        // ---- P -> per-wave LDS (C-layout -> A-fragment layout) ----
        #pragma unroll
        for (int u = 0; u < 4; ++u) {
            int col = 16 * u + l15;
            #pragma unroll
            for (int r = 0; r < 4; ++r) {
                int row = quad * 4 + r;
                Pw[row * 64 + (((col >> 3) ^ (row & 7)) * 8) + (col & 7)] = f2h(pr[u][r]);
            }
        }

        // ---- O += P V ----
        #pragma unroll
        for (int kc = 0; kc < 2; ++kc) {
            f16x8 ap = *(const f16x8*)&Pw[l15 * 64 + (((quad + 4 * kc) ^ sw) * 8)];
            #pragma unroll
            for (int nt = 0; nt < 4; ++nt) {
                int drow = 16 * nt + l15;
                f16x8 bv = *(const f16x8*)&Vlds[drow * 64 + (((quad + 4 * kc) ^ sw) * 8)];
                oacc[nt] = MFMA16(ap, bv, oacc[nt]);
            }
        }
        __syncthreads();
    }

    // ---- fused output projection: out_tile = (O/l) * Wo[h] ----
    const int b  = bh >> 4, hh = bh & 15;
    {
        const float* wo = Wo + (size_t)hh * D_ * D_;
        #pragma unroll
        for (int i = 0; i < 2; ++i) {
            int ch = tid + 256 * i;          // e = ch>>3, dc = ch&7
            int e = ch >> 3, dc = ch & 7;
            short8 vch;
            #pragma unroll
            for (int j = 0; j < 8; ++j)
                vch[j] = (short)f2h(wo[(size_t)(dc * 8 + j) * D_ + e]);
            *(short8*)&Klds[e * 64 + ((dc ^ (e & 7)) * 8)] = vch;
        }
    }
    #pragma unroll
    for (int nt = 0; nt < 4; ++nt) {
        int col = 16 * nt + l15;             // d
        #pragma unroll
        for (int r = 0; r < 4; ++r) {
            int row = quad * 4 + r;          // q
            Pw[row * 64 + (((col >> 3) ^ (row & 7)) * 8) + (col & 7)] =
                f2h(oacc[nt][r] / lrun[r]);
        }
    }
    __syncthreads();    // Wo^T staging visible to all waves

    f16x8 ao0 = *(const f16x8*)&Pw[l15 * 64 + (((quad + 0) ^ sw) * 8)];
    f16x8 ao1 = *(const f16x8*)&Pw[l15 * 64 + (((quad + 4) ^ sw) * 8)];
    f32x4 oo[4];
    #pragma unroll
    for (int nt = 0; nt < 4; ++nt) {
        oo[nt] = (f32x4){0.f, 0.f, 0.f, 0.f};
        int erow = 16 * nt + l15;
        f16x8 b0 = *(const f16x8*)&Klds[erow * 64 + (((quad + 0) ^ (erow & 7)) * 8)];
        f16x8 b1 = *(const f16x8*)&Klds[erow * 64 + (((quad + 4) ^ (erow & 7)) * 8)];
        oo[nt] = MFMA16(ao0, b0, oo[nt]);
        oo[nt] = MFMA16(ao1, b1, oo[nt]);
    }
    #pragma unroll
    for (int nt = 0; nt < 4; ++nt) {
        #pragma unroll
        for (int r = 0; r < 4; ++r) {
            int qg = qt * 64 + w * 16 + quad * 4 + r;
            int e  = 16 * nt + l15;
            out[((size_t)b * T_ + qg) * E_ + hh * D_ + e] = oo[nt][r];
        }
    }
}

// ---------------------------------------------------------------------------
extern "C" void kernel_launch(void* const* d_in, const int* in_sizes, int n_in,
                              void* d_out, int out_size, void* d_ws, size_t ws_size,
                              hipStream_t stream)
{
    const float* src = (const float*)d_in[0];
    const float* tgt = (const float*)d_in[1];
    const float* Wq  = (const float*)d_in[2];
    const float* Wv  = (const float*)d_in[3];
    const float* Wo  = (const float*)d_in[4];
    const float* Wih = (const float*)d_in[5];
    const float* Whh = (const float*)d_in[6];
    const float* bih = (const float*)d_in[7];
    const float* bhh = (const float*)d_in[8];
    float* out = (float*)d_out;

    char* ws = (char*)d_ws;
    u16* qh  = (u16*)(ws);                             // [bh][t][d] 16 MB
    u16* vh  = (u16*)(ws + (size_t)16 * 1024 * 1024);  // V^T [bh][d][t] 16 MB
    u16* nwh = (u16*)(ws + (size_t)32 * 1024 * 1024);  // [bh][t][d] 16 MB

    (void)in_sizes; (void)n_in; (void)out_size; (void)ws_size;

    // blocks [0,128) = RNN chains; [128, 128+4096) = q/v projection
    proj_rnn_kernel<<<dim3(BH_ + 4096), 256, 0, stream>>>(
        src, tgt, Wq, Wv, Wih, Whh, bih, bhh, qh, vh, nwh);
    attn_kernel<<<dim3(16, BH_), 256, 0, stream>>>(qh, nwh, vh, Wo, out);
}